// Round 7
// baseline (313.879 us; speedup 1.0000x reference)
//
#include <hip/hip_runtime.h>
#include <cstdint>
#include <cstddef>

#define LOG2E 1.4426950408889634f

constexpr int Dm  = 192;
constexpr int DEe = 96;

typedef unsigned short u16;
typedef __attribute__((ext_vector_type(8))) short short8v;
typedef __attribute__((ext_vector_type(4))) float f32x4;

__device__ __forceinline__ u16 f2bf(float f) {
    uint32_t u = __builtin_bit_cast(uint32_t, f);
    uint32_t r = (u + 0x7FFF + ((u >> 16) & 1)) >> 16;
    return (u16)r;
}
__device__ __forceinline__ float bf2f(u16 h) {
    uint32_t u = ((uint32_t)h) << 16;
    return __builtin_bit_cast(float, u);
}
__device__ __forceinline__ short8v ntl8(const u16* p) {
    return __builtin_nontemporal_load((const short8v*)p);
}

// ---------------------------------------------------------------- utilities
__global__ void zero_ints(int* __restrict__ p, int n) {
    int i = blockIdx.x * blockDim.x + threadIdx.x;
    if (i < n) p[i] = 0;
}

__global__ void count_deg(const int* __restrict__ ei, int E, int* __restrict__ deg) {
    int e = blockIdx.x * blockDim.x + threadIdx.x;
    if (e < E) atomicAdd(&deg[ei[E + e]], 1);
}

__global__ __launch_bounds__(1024) void scan_kernel(const int* __restrict__ deg, int N,
                                                    int* __restrict__ offs) {
    __shared__ int sp[1024];
    int t = threadIdx.x;
    int per = (N + 1023) >> 10;
    int base = t * per;
    int sum = 0;
    for (int i = 0; i < per; ++i) {
        int idx = base + i;
        if (idx < N) sum += deg[idx];
    }
    sp[t] = sum;
    __syncthreads();
    for (int off = 1; off < 1024; off <<= 1) {
        int v = (t >= off) ? sp[t - off] : 0;
        __syncthreads();
        sp[t] += v;
        __syncthreads();
    }
    int run = sp[t] - sum;
    for (int i = 0; i < per; ++i) {
        int idx = base + i;
        if (idx < N) { offs[idx] = run; run += deg[idx]; }
    }
    if (t == 1023) offs[N] = sp[1023];
}

// fp32 -> bf16 (vectorized float4 -> ushort4)
__global__ void xconv(const float* __restrict__ x, int n4, u16* __restrict__ xb) {
    int i = blockIdx.x * blockDim.x + threadIdx.x;
    if (i >= n4) return;
    float4 v = ((const float4*)x)[i];
    ushort4 o;
    o.x = f2bf(v.x); o.y = f2bf(v.y); o.z = f2bf(v.z); o.w = f2bf(v.w);
    ((ushort4*)xb)[i] = o;
}

// all weight transposes+conversions in one launch. Wt layouts: [Nout][K] bf16.
__global__ void prep_w(const float* __restrict__ Wq, const float* __restrict__ Wk,
                       const float* __restrict__ Wv, const float* __restrict__ Wo,
                       const float* __restrict__ Wg, const float* __restrict__ Wf1,
                       const float* __restrict__ Wf2,
                       u16* __restrict__ Wqkvt, u16* __restrict__ Wot,
                       u16* __restrict__ Wgt, u16* __restrict__ Wf1t,
                       u16* __restrict__ Wf2t) {
    int idx = blockIdx.x * blockDim.x + threadIdx.x;
    if (idx < 110592) {                    // QKV: [576][192]
        int n = idx / 192, k = idx % 192;
        const float* W = n < 192 ? Wq : (n < 384 ? Wk : Wv);
        Wqkvt[idx] = f2bf(W[(size_t)k * 192 + (n % 192)]);
    } else if (idx < 147456) {             // Wo: [192][192]
        int i = idx - 110592;
        int n = i / 192, k = i % 192;
        Wot[i] = f2bf(Wo[(size_t)k * 192 + n]);
    } else if (idx < 221184) {             // Wg: [192][384]
        int i = idx - 147456;
        int n = i / 384, k = i % 384;
        Wgt[i] = f2bf(Wg[(size_t)k * 192 + n]);
    } else if (idx < 294912) {             // Wf1: [384][192]
        int i = idx - 221184;
        int n = i / 192, k = i % 192;
        Wf1t[i] = f2bf(Wf1[(size_t)k * 384 + n]);
    } else if (idx < 368640) {             // Wf2: [192][384]
        int i = idx - 294912;
        int n = i / 384, k = i % 384;
        Wf2t[i] = f2bf(Wf2[(size_t)k * 192 + n]);
    }
}

// ---------------------------------------- edge prep: ef@We + CSR scatter
__global__ __launch_bounds__(256) void edge_prep(
    const int* __restrict__ ei, int E,
    const float* __restrict__ ef, const float* __restrict__ We,
    const int* __restrict__ offs, int* __restrict__ cur,
    float* __restrict__ scb, int* __restrict__ sbuf)
{
    __shared__ float We_s[DEe * 8];
    __shared__ float ef_s[32][100];
    int tid = threadIdx.x;
    for (int i = tid; i < DEe * 8; i += 256) We_s[i] = We[i];
    int e0 = blockIdx.x * 32;
    #pragma unroll
    for (int rep = 0; rep < 3; ++rep) {
        int idx = tid + 256 * rep;
        int el = idx / 24, c4 = idx % 24;
        int e = e0 + el;
        float4 v = make_float4(0.f, 0.f, 0.f, 0.f);
        if (e < E) v = *(const float4*)&ef[(size_t)e * DEe + c4 * 4];
        *(float4*)&ef_s[el][c4 * 4] = v;
    }
    __syncthreads();
    int el = tid >> 3, h = tid & 7;
    int e = e0 + el;
    if (e >= E) return;
    float epj = 0.f;
    #pragma unroll 8
    for (int i = 0; i < DEe; ++i) epj += ef_s[el][i] * We_s[i * 8 + h];

    int lane = tid & 63;
    int pos = 0;
    if (h == 0) {
        int dst = ei[E + e];
        pos = offs[dst] + atomicAdd(&cur[dst], 1);
    }
    pos = __shfl(pos, lane & 56, 64);
    scb[(size_t)pos * 8 + h] = epj * LOG2E;
    if (h == 0) sbuf[pos] = ei[e];   // src
}

// ---------------------------------------- fused score + softmax + PV per node
__global__ __launch_bounds__(256) void agg_fused(
    const u16* __restrict__ qkv, const float* __restrict__ scb,
    const int* __restrict__ sbuf, const int* __restrict__ offs,
    int N, u16* __restrict__ aggb)
{
    int node = blockIdx.x * 4 + (threadIdx.x >> 6);
    if (node >= N) return;
    int lane = threadIdx.x & 63;
    int h = lane >> 3;
    int di = (3 * lane) >> 1;
    int odd = lane & 1;

    const uint32_t* qrow = (const uint32_t*)(qkv + (size_t)node * 576);
    uint32_t qd0 = qrow[di], qd1 = qrow[di + 1];
    float q0, q1, q2;
    if (!odd) { q0 = bf2f(qd0 & 0xffff); q1 = bf2f(qd0 >> 16); q2 = bf2f(qd1 & 0xffff); }
    else      { q0 = bf2f(qd0 >> 16);    q1 = bf2f(qd1 & 0xffff); q2 = bf2f(qd1 >> 16); }

    float den = 0.f, a0 = 0.f, a1 = 0.f, a2 = 0.f;
    int beg = offs[node], end = offs[node + 1];

    uint32_t kd0_n = 0, kd1_n = 0, vd0_n = 0, vd1_n = 0; float ep_n = 0.f;
    if (beg < end) {
        int src = sbuf[beg];
        const uint32_t* kr = (const uint32_t*)(qkv + (size_t)src * 576 + 192);
        kd0_n = kr[di]; kd1_n = kr[di + 1];
        const uint32_t* vr = (const uint32_t*)(qkv + (size_t)src * 576 + 384);
        vd0_n = vr[di]; vd1_n = vr[di + 1];
        ep_n = scb[(size_t)beg * 8 + h];
    }

    for (int idx = beg; idx < end; ++idx) {
        uint32_t kd0 = kd0_n, kd1 = kd1_n, vd0 = vd0_n, vd1 = vd1_n;
        float ep = ep_n;
        if (idx + 1 < end) {
            int src = sbuf[idx + 1];
            const uint32_t* kr = (const uint32_t*)(qkv + (size_t)src * 576 + 192);
            kd0_n = kr[di]; kd1_n = kr[di + 1];
            const uint32_t* vr = (const uint32_t*)(qkv + (size_t)src * 576 + 384);
            vd0_n = vr[di]; vd1_n = vr[di + 1];
            ep_n = scb[(size_t)(idx + 1) * 8 + h];
        }
        float k0, k1, k2, v0, v1, v2;
        if (!odd) {
            k0 = bf2f(kd0 & 0xffff); k1 = bf2f(kd0 >> 16); k2 = bf2f(kd1 & 0xffff);
            v0 = bf2f(vd0 & 0xffff); v1 = bf2f(vd0 >> 16); v2 = bf2f(vd1 & 0xffff);
        } else {
            k0 = bf2f(kd0 >> 16); k1 = bf2f(kd1 & 0xffff); k2 = bf2f(kd1 >> 16);
            v0 = bf2f(vd0 >> 16); v1 = bf2f(vd1 & 0xffff); v2 = bf2f(vd1 >> 16);
        }
        float pd = q0 * k0 + q1 * k1 + q2 * k2;
        pd += __shfl_xor(pd, 1, 64);
        pd += __shfl_xor(pd, 2, 64);
        pd += __shfl_xor(pd, 4, 64);
        float p = exp2f(pd * 0.2944885836f + ep);
        den += p;
        a0 += p * v0; a1 += p * v1; a2 += p * v2;
    }
    float rden = 1.f / (den + 1e-8f);
    u16* og = aggb + (size_t)node * Dm;
    int b0 = 3 * lane;
    og[b0]     = f2bf(a0 * rden);
    og[b0 + 1] = f2bf(a1 * rden);
    og[b0 + 2] = f2bf(a2 * rden);
}

// ---------------------------------------- zero-LDS fragment GEMM: QKV
// Streaming A (xb) via non-temporal loads; weights stay cache-resident.
__global__ __launch_bounds__(256) void qkv_gemm(
    const u16* __restrict__ xb, int M,
    const u16* __restrict__ Wt, u16* __restrict__ qkvb)
{
    int tid = threadIdx.x;
    int m0 = blockIdx.x * 64, n0 = blockIdx.y * 192;
    int w = tid >> 6, lane = tid & 63;
    int c16 = lane & 15, hi2 = lane >> 4, kof = hi2 * 8;

    int rcm[4];
    #pragma unroll
    for (int mr = 0; mr < 4; ++mr) {
        int r = m0 + mr * 16 + c16;
        rcm[mr] = r < M ? r : M - 1;
    }

    f32x4 acc[4][3];
    #pragma unroll
    for (int mr = 0; mr < 4; ++mr)
        #pragma unroll
        for (int nr = 0; nr < 3; ++nr) acc[mr][nr] = (f32x4)(0.f);

    #pragma unroll 1
    for (int ks = 0; ks < 6; ++ks) {
        short8v af[4], bfr[3];
        #pragma unroll
        for (int mr = 0; mr < 4; ++mr)
            af[mr] = ntl8(xb + (size_t)rcm[mr] * 192 + ks * 32 + kof);
        #pragma unroll
        for (int nr = 0; nr < 3; ++nr)
            bfr[nr] = *(const short8v*)(Wt + (size_t)(n0 + w * 48 + nr * 16 + c16) * 192 + ks * 32 + kof);
        #pragma unroll
        for (int mr = 0; mr < 4; ++mr)
            #pragma unroll
            for (int nr = 0; nr < 3; ++nr)
                acc[mr][nr] = __builtin_amdgcn_mfma_f32_16x16x32_bf16(
                    af[mr], bfr[nr], acc[mr][nr], 0, 0, 0);
    }

    #pragma unroll
    for (int mr = 0; mr < 4; ++mr)
        #pragma unroll
        for (int reg = 0; reg < 4; ++reg) {
            int r = m0 + mr * 16 + hi2 * 4 + reg;
            if (r >= M) continue;
            #pragma unroll
            for (int nr = 0; nr < 3; ++nr)
                __builtin_nontemporal_store(
                    f2bf(acc[mr][nr][reg]),
                    qkvb + (size_t)r * 576 + n0 + w * 48 + nr * 16 + c16);
        }
}

// ---------------------------------------- fused node chain (BM=64, rolled,
// non-temporal streaming loads/stores so weights stay L2-resident)
__global__ __launch_bounds__(256) void chain_fused(
    const u16* __restrict__ aggb, const u16* __restrict__ xb, int M,
    const u16* __restrict__ Wot, const float* __restrict__ bo,
    const u16* __restrict__ Wgt, const float* __restrict__ bg,
    const float* __restrict__ l1s, const float* __restrict__ l1b,
    const u16* __restrict__ Wf1t, const float* __restrict__ bf1,
    const u16* __restrict__ Wf2t, const float* __restrict__ bf2,
    const float* __restrict__ l2s, const float* __restrict__ l2b,
    float* __restrict__ out)
{
    __shared__ __align__(16) short Ybuf[64 * 200];   // o, then y (stride 200)
    __shared__ __align__(16) short Fbuf[64 * 392];   // ff1 (stride 392)
    __shared__ float red[2][4][64];

    int tid = threadIdx.x;
    int m0 = blockIdx.x * 64;
    int w = tid >> 6, lane = tid & 63;
    int c16 = lane & 15, hi2 = lane >> 4, kof = hi2 * 8;

    int rcm[4];
    #pragma unroll
    for (int mr = 0; mr < 4; ++mr) {
        int r = m0 + mr * 16 + c16;
        rcm[mr] = r < M ? r : M - 1;
    }

    // ---- stage0: o = agg @ Wo + bo
    f32x4 oacc[4][3];
    #pragma unroll
    for (int mr = 0; mr < 4; ++mr)
        #pragma unroll
        for (int nr = 0; nr < 3; ++nr) oacc[mr][nr] = (f32x4)(0.f);
    #pragma unroll 1
    for (int ks = 0; ks < 6; ++ks) {
        short8v af[4], bfr[3];
        #pragma unroll
        for (int mr = 0; mr < 4; ++mr)
            af[mr] = ntl8(aggb + (size_t)rcm[mr] * 192 + ks * 32 + kof);
        #pragma unroll
        for (int nr = 0; nr < 3; ++nr)
            bfr[nr] = *(const short8v*)(Wot + (size_t)(w * 48 + nr * 16 + c16) * 192 + ks * 32 + kof);
        #pragma unroll
        for (int mr = 0; mr < 4; ++mr)
            #pragma unroll
            for (int nr = 0; nr < 3; ++nr)
                oacc[mr][nr] = __builtin_amdgcn_mfma_f32_16x16x32_bf16(
                    af[mr], bfr[nr], oacc[mr][nr], 0, 0, 0);
    }
    #pragma unroll
    for (int nr = 0; nr < 3; ++nr) {
        int col = w * 48 + nr * 16 + c16;
        float b = bo[col];
        #pragma unroll
        for (int mr = 0; mr < 4; ++mr)
            #pragma unroll
            for (int reg = 0; reg < 4; ++reg) {
                oacc[mr][nr][reg] += b;
                int row = mr * 16 + hi2 * 4 + reg;
                Ybuf[row * 200 + col] = (short)f2bf(oacc[mr][nr][reg]);
            }
    }
    __syncthreads();

    // ---- stage1: z = [o,x] @ Wg + bg; gate; LN1 -> y
    f32x4 zacc[4][3];
    #pragma unroll
    for (int mr = 0; mr < 4; ++mr)
        #pragma unroll
        for (int nr = 0; nr < 3; ++nr) zacc[mr][nr] = (f32x4)(0.f);
    #pragma unroll 1
    for (int ks = 0; ks < 6; ++ks) {          // o half (from LDS)
        short8v af[4], bfr[3];
        #pragma unroll
        for (int mr = 0; mr < 4; ++mr)
            af[mr] = *(const short8v*)&Ybuf[(mr * 16 + c16) * 200 + ks * 32 + kof];
        #pragma unroll
        for (int nr = 0; nr < 3; ++nr)
            bfr[nr] = *(const short8v*)(Wgt + (size_t)(w * 48 + nr * 16 + c16) * 384 + ks * 32 + kof);
        #pragma unroll
        for (int mr = 0; mr < 4; ++mr)
            #pragma unroll
            for (int nr = 0; nr < 3; ++nr)
                zacc[mr][nr] = __builtin_amdgcn_mfma_f32_16x16x32_bf16(
                    af[mr], bfr[nr], zacc[mr][nr], 0, 0, 0);
    }
    #pragma unroll 1
    for (int ks = 0; ks < 6; ++ks) {          // x half (from global, streaming)
        short8v af[4], bfr[3];
        #pragma unroll
        for (int mr = 0; mr < 4; ++mr)
            af[mr] = ntl8(xb + (size_t)rcm[mr] * 192 + ks * 32 + kof);
        #pragma unroll
        for (int nr = 0; nr < 3; ++nr)
            bfr[nr] = *(const short8v*)(Wgt + (size_t)(w * 48 + nr * 16 + c16) * 384 + 192 + ks * 32 + kof);
        #pragma unroll
        for (int mr = 0; mr < 4; ++mr)
            #pragma unroll
            for (int nr = 0; nr < 3; ++nr)
                zacc[mr][nr] = __builtin_amdgcn_mfma_f32_16x16x32_bf16(
                    af[mr], bfr[nr], zacc[mr][nr], 0, 0, 0);
    }
    float s1p[4][4], s2p[4][4];
    #pragma unroll
    for (int mr = 0; mr < 4; ++mr)
        #pragma unroll
        for (int reg = 0; reg < 4; ++reg) {
            int gr = m0 + mr * 16 + hi2 * 4 + reg;
            int rcR = gr < M ? gr : M - 1;
            float s1 = 0.f, s2 = 0.f;
            #pragma unroll
            for (int nr = 0; nr < 3; ++nr) {
                int col = w * 48 + nr * 16 + c16;
                float z = zacc[mr][nr][reg] + bg[col];
                float g = 1.f / (1.f + expf(-z));
                float xv = bf2f(__builtin_nontemporal_load(xb + (size_t)rcR * 192 + col));
                float val = g * oacc[mr][nr][reg] + (1.f - g) * xv;
                zacc[mr][nr][reg] = val;
                s1 += val; s2 += val * val;
            }
            #pragma unroll
            for (int mS = 1; mS < 16; mS <<= 1) {
                s1 += __shfl_xor(s1, mS, 64);
                s2 += __shfl_xor(s2, mS, 64);
            }
            s1p[mr][reg] = s1; s2p[mr][reg] = s2;
        }
    if (c16 == 0) {
        #pragma unroll
        for (int mr = 0; mr < 4; ++mr)
            #pragma unroll
            for (int reg = 0; reg < 4; ++reg) {
                int rowIdx = mr * 16 + hi2 * 4 + reg;
                red[0][w][rowIdx] = s1p[mr][reg];
                red[1][w][rowIdx] = s2p[mr][reg];
            }
    }
    __syncthreads();   // all stage1 Ybuf o-reads done; safe to overwrite with y
    #pragma unroll
    for (int mr = 0; mr < 4; ++mr)
        #pragma unroll
        for (int reg = 0; reg < 4; ++reg) {
            int rowIdx = mr * 16 + hi2 * 4 + reg;
            float S1 = red[0][0][rowIdx] + red[0][1][rowIdx] + red[0][2][rowIdx] + red[0][3][rowIdx];
            float S2 = red[1][0][rowIdx] + red[1][1][rowIdx] + red[1][2][rowIdx] + red[1][3][rowIdx];
            float mean = S1 * (1.f / 192.f);
            float var  = S2 * (1.f / 192.f) - mean * mean;
            float inv  = rsqrtf(var + 1e-5f);
            #pragma unroll
            for (int nr = 0; nr < 3; ++nr) {
                int col = w * 48 + nr * 16 + c16;
                float yv = (zacc[mr][nr][reg] - mean) * inv * l1s[col] + l1b[col];
                Ybuf[rowIdx * 200 + col] = (short)f2bf(yv);
            }
        }
    __syncthreads();

    // ---- stage2: t = silu(y @ Wf1 + bf1), cols w*96 + nr*16, nr<6
    f32x4 tacc[4][6];
    #pragma unroll
    for (int mr = 0; mr < 4; ++mr)
        #pragma unroll
        for (int nr = 0; nr < 6; ++nr) tacc[mr][nr] = (f32x4)(0.f);
    #pragma unroll 1
    for (int ks = 0; ks < 6; ++ks) {
        short8v af[4], bfr[6];
        #pragma unroll
        for (int mr = 0; mr < 4; ++mr)
            af[mr] = *(const short8v*)&Ybuf[(mr * 16 + c16) * 200 + ks * 32 + kof];
        #pragma unroll
        for (int nr = 0; nr < 6; ++nr)
            bfr[nr] = *(const short8v*)(Wf1t + (size_t)(w * 96 + nr * 16 + c16) * 192 + ks * 32 + kof);
        #pragma unroll
        for (int mr = 0; mr < 4; ++mr)
            #pragma unroll
            for (int nr = 0; nr < 6; ++nr)
                tacc[mr][nr] = __builtin_amdgcn_mfma_f32_16x16x32_bf16(
                    af[mr], bfr[nr], tacc[mr][nr], 0, 0, 0);
    }
    #pragma unroll
    for (int nr = 0; nr < 6; ++nr) {
        int col = w * 96 + nr * 16 + c16;
        float b = bf1[col];
        #pragma unroll
        for (int mr = 0; mr < 4; ++mr)
            #pragma unroll
            for (int reg = 0; reg < 4; ++reg) {
                float z = tacc[mr][nr][reg] + b;
                float t = z / (1.f + expf(-z));
                int row = mr * 16 + hi2 * 4 + reg;
                Fbuf[row * 392 + col] = (short)f2bf(t);
            }
    }
    __syncthreads();

    // ---- stage3: out = LN2(y + t @ Wf2 + bf2)
    f32x4 facc[4][3];
    #pragma unroll
    for (int mr = 0; mr < 4; ++mr)
        #pragma unroll
        for (int nr = 0; nr < 3; ++nr) facc[mr][nr] = (f32x4)(0.f);
    #pragma unroll 1
    for (int ks = 0; ks < 12; ++ks) {
        short8v af[4], bfr[3];
        #pragma unroll
        for (int mr = 0; mr < 4; ++mr)
            af[mr] = *(const short8v*)&Fbuf[(mr * 16 + c16) * 392 + ks * 32 + kof];
        #pragma unroll
        for (int nr = 0; nr < 3; ++nr)
            bfr[nr] = *(const short8v*)(Wf2t + (size_t)(w * 48 + nr * 16 + c16) * 384 + ks * 32 + kof);
        #pragma unroll
        for (int mr = 0; mr < 4; ++mr)
            #pragma unroll
            for (int nr = 0; nr < 3; ++nr)
                facc[mr][nr] = __builtin_amdgcn_mfma_f32_16x16x32_bf16(
                    af[mr], bfr[nr], facc[mr][nr], 0, 0, 0);
    }
    float s1q[4][4], s2q[4][4];
    #pragma unroll
    for (int mr = 0; mr < 4; ++mr)
        #pragma unroll
        for (int reg = 0; reg < 4; ++reg) {
            int rowIdx = mr * 16 + hi2 * 4 + reg;
            float s1 = 0.f, s2 = 0.f;
            #pragma unroll
            for (int nr = 0; nr < 3; ++nr) {
                int col = w * 48 + nr * 16 + c16;
                float val = facc[mr][nr][reg] + bf2[col] + bf2f((u16)Ybuf[rowIdx * 200 + col]);
                facc[mr][nr][reg] = val;
                s1 += val; s2 += val * val;
            }
            #pragma unroll
            for (int mS = 1; mS < 16; mS <<= 1) {
                s1 += __shfl_xor(s1, mS, 64);
                s2 += __shfl_xor(s2, mS, 64);
            }
            s1q[mr][reg] = s1; s2q[mr][reg] = s2;
        }
    if (c16 == 0) {
        #pragma unroll
        for (int mr = 0; mr < 4; ++mr)
            #pragma unroll
            for (int reg = 0; reg < 4; ++reg) {
                int rowIdx = mr * 16 + hi2 * 4 + reg;
                red[0][w][rowIdx] = s1q[mr][reg];
                red[1][w][rowIdx] = s2q[mr][reg];
            }
    }
    __syncthreads();
    #pragma unroll
    for (int mr = 0; mr < 4; ++mr)
        #pragma unroll
        for (int reg = 0; reg < 4; ++reg) {
            int rowIdx = mr * 16 + hi2 * 4 + reg;
            int r = m0 + rowIdx;
            if (r >= M) continue;
            float S1 = red[0][0][rowIdx] + red[0][1][rowIdx] + red[0][2][rowIdx] + red[0][3][rowIdx];
            float S2 = red[1][0][rowIdx] + red[1][1][rowIdx] + red[1][2][rowIdx] + red[1][3][rowIdx];
            float mean = S1 * (1.f / 192.f);
            float var  = S2 * (1.f / 192.f) - mean * mean;
            float inv  = rsqrtf(var + 1e-5f);
            #pragma unroll
            for (int nr = 0; nr < 3; ++nr) {
                int col = w * 48 + nr * 16 + c16;
                __builtin_nontemporal_store(
                    (facc[mr][nr][reg] - mean) * inv * l2s[col] + l2b[col],
                    out + (size_t)r * 192 + col);
            }
        }
}

// ---------------------------------------------------------------- launcher
extern "C" void kernel_launch(void* const* d_in, const int* in_sizes, int n_in,
                              void* d_out, int out_size, void* d_ws, size_t ws_size,
                              hipStream_t stream) {
    const float* x   = (const float*)d_in[0];
    const float* ef  = (const float*)d_in[1];
    const int*   ei  = (const int*)d_in[2];
    const float* Wq  = (const float*)d_in[3];
    const float* Wk  = (const float*)d_in[4];
    const float* Wv  = (const float*)d_in[5];
    const float* We  = (const float*)d_in[6];
    const float* Wo  = (const float*)d_in[7];
    const float* bo  = (const float*)d_in[8];
    const float* Wg  = (const float*)d_in[9];
    const float* bg  = (const float*)d_in[10];
    const float* l1s = (const float*)d_in[11];
    const float* l1b = (const float*)d_in[12];
    const float* Wf1 = (const float*)d_in[13];
    const float* bf1 = (const float*)d_in[14];
    const float* Wf2 = (const float*)d_in[15];
    const float* bf2 = (const float*)d_in[16];
    const float* l2s = (const float*)d_in[17];
    const float* l2b = (const float*)d_in[18];

    int N = in_sizes[0] / Dm;
    int E = in_sizes[1] / DEe;
    float* out = (float*)d_out;

    char* wp = (char*)d_ws;
    auto alloc = [&](size_t bytes) -> void* {
        void* p = wp;
        wp += (bytes + 255) & ~(size_t)255;
        return p;
    };
    size_t NF = (size_t)N * Dm;
    u16*   xb     = (u16*)alloc(NF * 2);
    u16*   qkvb   = (u16*)alloc((size_t)N * 576 * 2);
    u16*   aggb   = (u16*)alloc(NF * 2);
    float* scb    = (float*)alloc((size_t)E * 8 * 4);
    int*   sbuf   = (int*)  alloc((size_t)E * 4);
    int*   degcur = (int*)  alloc((size_t)2 * N * 4);
    int*   offs   = (int*)  alloc((size_t)(N + 1) * 4);
    u16*   Wqkvt  = (u16*)alloc((size_t)576 * 192 * 2);
    u16*   Wot    = (u16*)alloc((size_t)192 * 192 * 2);
    u16*   Wgt    = (u16*)alloc((size_t)192 * 384 * 2);
    u16*   Wf1t   = (u16*)alloc((size_t)384 * 192 * 2);
    u16*   Wf2t   = (u16*)alloc((size_t)192 * 384 * 2);
    int* deg = degcur;
    int* cur = degcur + N;

    int gm = (N + 63) / 64;

    prep_w<<<dim3(1440), 256, 0, stream>>>(Wq, Wk, Wv, Wo, Wg, Wf1, Wf2,
        Wqkvt, Wot, Wgt, Wf1t, Wf2t);
    xconv<<<dim3((N * Dm / 4 + 255) / 256), 256, 0, stream>>>(x, N * Dm / 4, xb);
    zero_ints<<<dim3((2 * N + 255) / 256), 256, 0, stream>>>(degcur, 2 * N);
    count_deg<<<dim3((E + 255) / 256), 256, 0, stream>>>(ei, E, deg);
    scan_kernel<<<dim3(1), 1024, 0, stream>>>(deg, N, offs);

    qkv_gemm<<<dim3(gm, 3), 256, 0, stream>>>(xb, N, Wqkvt, qkvb);

    edge_prep<<<dim3((E + 31) / 32), 256, 0, stream>>>(ei, E, ef, We,
        offs, cur, scb, sbuf);
    agg_fused<<<dim3((N + 3) / 4), 256, 0, stream>>>(qkvb, scb, sbuf, offs, N, aggb);

    chain_fused<<<dim3(gm), 256, 0, stream>>>(aggb, xb, N,
        Wot, bo, Wgt, bg, l1s, l1b, Wf1t, bf1, Wf2t, bf2, l2s, l2b, out);
}

// Round 8
// 285.897 us; speedup vs baseline: 1.0979x; 1.0979x over previous
//
#include <hip/hip_runtime.h>
#include <cstdint>
#include <cstddef>

#define LOG2E 1.4426950408889634f

constexpr int Dm  = 192;
constexpr int DEe = 96;

typedef unsigned short u16;
typedef __attribute__((ext_vector_type(8))) short short8v;
typedef __attribute__((ext_vector_type(4))) float f32x4;

__device__ __forceinline__ u16 f2bf(float f) {
    uint32_t u = __builtin_bit_cast(uint32_t, f);
    uint32_t r = (u + 0x7FFF + ((u >> 16) & 1)) >> 16;
    return (u16)r;
}
__device__ __forceinline__ float bf2f(u16 h) {
    uint32_t u = ((uint32_t)h) << 16;
    return __builtin_bit_cast(float, u);
}

// ---------------------------------------------------------------- utilities
__global__ void zero_ints(int* __restrict__ p, int n) {
    int i = blockIdx.x * blockDim.x + threadIdx.x;
    if (i < n) p[i] = 0;
}

__global__ void count_deg(const int* __restrict__ ei, int E, int* __restrict__ deg) {
    int e = blockIdx.x * blockDim.x + threadIdx.x;
    if (e < E) atomicAdd(&deg[ei[E + e]], 1);
}

__global__ __launch_bounds__(1024) void scan_kernel(const int* __restrict__ deg, int N,
                                                    int* __restrict__ offs) {
    __shared__ int sp[1024];
    int t = threadIdx.x;
    int per = (N + 1023) >> 10;
    int base = t * per;
    int sum = 0;
    for (int i = 0; i < per; ++i) {
        int idx = base + i;
        if (idx < N) sum += deg[idx];
    }
    sp[t] = sum;
    __syncthreads();
    for (int off = 1; off < 1024; off <<= 1) {
        int v = (t >= off) ? sp[t - off] : 0;
        __syncthreads();
        sp[t] += v;
        __syncthreads();
    }
    int run = sp[t] - sum;
    for (int i = 0; i < per; ++i) {
        int idx = base + i;
        if (idx < N) { offs[idx] = run; run += deg[idx]; }
    }
    if (t == 1023) offs[N] = sp[1023];
}

// fp32 -> bf16 (vectorized float4 -> ushort4)
__global__ void xconv(const float* __restrict__ x, int n4, u16* __restrict__ xb) {
    int i = blockIdx.x * blockDim.x + threadIdx.x;
    if (i >= n4) return;
    float4 v = ((const float4*)x)[i];
    ushort4 o;
    o.x = f2bf(v.x); o.y = f2bf(v.y); o.z = f2bf(v.z); o.w = f2bf(v.w);
    ((ushort4*)xb)[i] = o;
}

// all weight transposes+conversions in one launch. Wt layouts: [Nout][K] bf16.
__global__ void prep_w(const float* __restrict__ Wq, const float* __restrict__ Wk,
                       const float* __restrict__ Wv, const float* __restrict__ Wo,
                       const float* __restrict__ Wg, const float* __restrict__ Wf1,
                       const float* __restrict__ Wf2,
                       u16* __restrict__ Wqkvt, u16* __restrict__ Wot,
                       u16* __restrict__ Wgt, u16* __restrict__ Wf1t,
                       u16* __restrict__ Wf2t) {
    int idx = blockIdx.x * blockDim.x + threadIdx.x;
    if (idx < 110592) {                    // QKV: [576][192]
        int n = idx / 192, k = idx % 192;
        const float* W = n < 192 ? Wq : (n < 384 ? Wk : Wv);
        Wqkvt[idx] = f2bf(W[(size_t)k * 192 + (n % 192)]);
    } else if (idx < 147456) {             // Wo: [192][192]
        int i = idx - 110592;
        int n = i / 192, k = i % 192;
        Wot[i] = f2bf(Wo[(size_t)k * 192 + n]);
    } else if (idx < 221184) {             // Wg: [192][384]
        int i = idx - 147456;
        int n = i / 384, k = i % 384;
        Wgt[i] = f2bf(Wg[(size_t)k * 192 + n]);
    } else if (idx < 294912) {             // Wf1: [384][192]
        int i = idx - 221184;
        int n = i / 192, k = i % 192;
        Wf1t[i] = f2bf(Wf1[(size_t)k * 384 + n]);
    } else if (idx < 368640) {             // Wf2: [192][384]
        int i = idx - 294912;
        int n = i / 384, k = i % 384;
        Wf2t[i] = f2bf(Wf2[(size_t)k * 192 + n]);
    }
}

// ---------------------------------------- edge prep: ef@We + CSR scatter
__global__ __launch_bounds__(256) void edge_prep(
    const int* __restrict__ ei, int E,
    const float* __restrict__ ef, const float* __restrict__ We,
    const int* __restrict__ offs, int* __restrict__ cur,
    float* __restrict__ scb, int* __restrict__ sbuf)
{
    __shared__ float We_s[DEe * 8];
    __shared__ float ef_s[32][100];
    int tid = threadIdx.x;
    for (int i = tid; i < DEe * 8; i += 256) We_s[i] = We[i];
    int e0 = blockIdx.x * 32;
    #pragma unroll
    for (int rep = 0; rep < 3; ++rep) {
        int idx = tid + 256 * rep;
        int el = idx / 24, c4 = idx % 24;
        int e = e0 + el;
        float4 v = make_float4(0.f, 0.f, 0.f, 0.f);
        if (e < E) v = *(const float4*)&ef[(size_t)e * DEe + c4 * 4];
        *(float4*)&ef_s[el][c4 * 4] = v;
    }
    __syncthreads();
    int el = tid >> 3, h = tid & 7;
    int e = e0 + el;
    if (e >= E) return;
    float epj = 0.f;
    #pragma unroll 8
    for (int i = 0; i < DEe; ++i) epj += ef_s[el][i] * We_s[i * 8 + h];

    int lane = tid & 63;
    int pos = 0;
    if (h == 0) {
        int dst = ei[E + e];
        pos = offs[dst] + atomicAdd(&cur[dst], 1);
    }
    pos = __shfl(pos, lane & 56, 64);
    scb[(size_t)pos * 8 + h] = epj * LOG2E;
    if (h == 0) sbuf[pos] = ei[e];   // src
}

// ---------------------------------------- fused score + softmax + PV per node
__global__ __launch_bounds__(256) void agg_fused(
    const u16* __restrict__ qkv, const float* __restrict__ scb,
    const int* __restrict__ sbuf, const int* __restrict__ offs,
    int N, u16* __restrict__ aggb)
{
    int node = blockIdx.x * 4 + (threadIdx.x >> 6);
    if (node >= N) return;
    int lane = threadIdx.x & 63;
    int h = lane >> 3;
    int di = (3 * lane) >> 1;
    int odd = lane & 1;

    const uint32_t* qrow = (const uint32_t*)(qkv + (size_t)node * 576);
    uint32_t qd0 = qrow[di], qd1 = qrow[di + 1];
    float q0, q1, q2;
    if (!odd) { q0 = bf2f(qd0 & 0xffff); q1 = bf2f(qd0 >> 16); q2 = bf2f(qd1 & 0xffff); }
    else      { q0 = bf2f(qd0 >> 16);    q1 = bf2f(qd1 & 0xffff); q2 = bf2f(qd1 >> 16); }

    float den = 0.f, a0 = 0.f, a1 = 0.f, a2 = 0.f;
    int beg = offs[node], end = offs[node + 1];

    uint32_t kd0_n = 0, kd1_n = 0, vd0_n = 0, vd1_n = 0; float ep_n = 0.f;
    if (beg < end) {
        int src = sbuf[beg];
        const uint32_t* kr = (const uint32_t*)(qkv + (size_t)src * 576 + 192);
        kd0_n = kr[di]; kd1_n = kr[di + 1];
        const uint32_t* vr = (const uint32_t*)(qkv + (size_t)src * 576 + 384);
        vd0_n = vr[di]; vd1_n = vr[di + 1];
        ep_n = scb[(size_t)beg * 8 + h];
    }

    for (int idx = beg; idx < end; ++idx) {
        uint32_t kd0 = kd0_n, kd1 = kd1_n, vd0 = vd0_n, vd1 = vd1_n;
        float ep = ep_n;
        if (idx + 1 < end) {
            int src = sbuf[idx + 1];
            const uint32_t* kr = (const uint32_t*)(qkv + (size_t)src * 576 + 192);
            kd0_n = kr[di]; kd1_n = kr[di + 1];
            const uint32_t* vr = (const uint32_t*)(qkv + (size_t)src * 576 + 384);
            vd0_n = vr[di]; vd1_n = vr[di + 1];
            ep_n = scb[(size_t)(idx + 1) * 8 + h];
        }
        float k0, k1, k2, v0, v1, v2;
        if (!odd) {
            k0 = bf2f(kd0 & 0xffff); k1 = bf2f(kd0 >> 16); k2 = bf2f(kd1 & 0xffff);
            v0 = bf2f(vd0 & 0xffff); v1 = bf2f(vd0 >> 16); v2 = bf2f(vd1 & 0xffff);
        } else {
            k0 = bf2f(kd0 >> 16); k1 = bf2f(kd1 & 0xffff); k2 = bf2f(kd1 >> 16);
            v0 = bf2f(vd0 >> 16); v1 = bf2f(vd1 & 0xffff); v2 = bf2f(vd1 >> 16);
        }
        float pd = q0 * k0 + q1 * k1 + q2 * k2;
        pd += __shfl_xor(pd, 1, 64);
        pd += __shfl_xor(pd, 2, 64);
        pd += __shfl_xor(pd, 4, 64);
        float p = exp2f(pd * 0.2944885836f + ep);
        den += p;
        a0 += p * v0; a1 += p * v1; a2 += p * v2;
    }
    float rden = 1.f / (den + 1e-8f);
    u16* og = aggb + (size_t)node * Dm;
    int b0 = 3 * lane;
    og[b0]     = f2bf(a0 * rden);
    og[b0 + 1] = f2bf(a1 * rden);
    og[b0 + 2] = f2bf(a2 * rden);
}

// ---------------------------------------- zero-LDS fragment GEMM: QKV (BM=128)
// 512 threads = 8 waves: wave w -> rows [wr*64), cols [wc*48) of the 128x192 tile
__global__ __launch_bounds__(512) void qkv_gemm(
    const u16* __restrict__ xb, int M,
    const u16* __restrict__ Wt, u16* __restrict__ qkvb)
{
    int tid = threadIdx.x;
    int m0 = blockIdx.x * 128, n0 = blockIdx.y * 192;
    int w = tid >> 6, lane = tid & 63;
    int wr = w >> 2, wc = w & 3;
    int c16 = lane & 15, hi2 = lane >> 4, kof = hi2 * 8;
    int rbase = m0 + wr * 64;

    int rcm[4];
    #pragma unroll
    for (int mr = 0; mr < 4; ++mr) {
        int r = rbase + mr * 16 + c16;
        rcm[mr] = r < M ? r : M - 1;
    }

    f32x4 acc[4][3];
    #pragma unroll
    for (int mr = 0; mr < 4; ++mr)
        #pragma unroll
        for (int nr = 0; nr < 3; ++nr) acc[mr][nr] = (f32x4)(0.f);

    #pragma unroll 1
    for (int ks = 0; ks < 6; ++ks) {
        short8v af[4], bfr[3];
        #pragma unroll
        for (int mr = 0; mr < 4; ++mr)
            af[mr] = *(const short8v*)(xb + (size_t)rcm[mr] * 192 + ks * 32 + kof);
        #pragma unroll
        for (int nr = 0; nr < 3; ++nr)
            bfr[nr] = *(const short8v*)(Wt + (size_t)(n0 + wc * 48 + nr * 16 + c16) * 192 + ks * 32 + kof);
        #pragma unroll
        for (int mr = 0; mr < 4; ++mr)
            #pragma unroll
            for (int nr = 0; nr < 3; ++nr)
                acc[mr][nr] = __builtin_amdgcn_mfma_f32_16x16x32_bf16(
                    af[mr], bfr[nr], acc[mr][nr], 0, 0, 0);
    }

    #pragma unroll
    for (int mr = 0; mr < 4; ++mr)
        #pragma unroll
        for (int reg = 0; reg < 4; ++reg) {
            int r = rbase + mr * 16 + hi2 * 4 + reg;
            if (r >= M) continue;
            #pragma unroll
            for (int nr = 0; nr < 3; ++nr)
                qkvb[(size_t)r * 576 + n0 + wc * 48 + nr * 16 + c16] =
                    f2bf(acc[mr][nr][reg]);
        }
}

// ---------------------------------------- fused node chain (BM=128, 8 waves):
// halves per-dispatch weight re-reads vs BM=64 (full weight set read per block)
__global__ __launch_bounds__(512) void chain_fused(
    const u16* __restrict__ aggb, const u16* __restrict__ xb, int M,
    const u16* __restrict__ Wot, const float* __restrict__ bo,
    const u16* __restrict__ Wgt, const float* __restrict__ bg,
    const float* __restrict__ l1s, const float* __restrict__ l1b,
    const u16* __restrict__ Wf1t, const float* __restrict__ bf1,
    const u16* __restrict__ Wf2t, const float* __restrict__ bf2,
    const float* __restrict__ l2s, const float* __restrict__ l2b,
    float* __restrict__ out)
{
    __shared__ __align__(16) short Ybuf[128 * 200];   // 51.2 KB: o, then y
    __shared__ __align__(16) short Fbuf[128 * 392];   // 100.4 KB: ff1
    __shared__ float red[2][4][128];                  // 4 KB

    int tid = threadIdx.x;
    int m0 = blockIdx.x * 128;
    int w = tid >> 6, lane = tid & 63;
    int wr = w >> 2, wc = w & 3;
    int c16 = lane & 15, hi2 = lane >> 4, kof = hi2 * 8;
    int rbase = m0 + wr * 64;
    int lbase = wr * 64;                               // block-local row base

    int rcm[4];
    #pragma unroll
    for (int mr = 0; mr < 4; ++mr) {
        int r = rbase + mr * 16 + c16;
        rcm[mr] = r < M ? r : M - 1;
    }

    // ---- stage0: o = agg @ Wo + bo
    f32x4 oacc[4][3];
    #pragma unroll
    for (int mr = 0; mr < 4; ++mr)
        #pragma unroll
        for (int nr = 0; nr < 3; ++nr) oacc[mr][nr] = (f32x4)(0.f);
    #pragma unroll 1
    for (int ks = 0; ks < 6; ++ks) {
        short8v af[4], bfr[3];
        #pragma unroll
        for (int mr = 0; mr < 4; ++mr)
            af[mr] = *(const short8v*)(aggb + (size_t)rcm[mr] * 192 + ks * 32 + kof);
        #pragma unroll
        for (int nr = 0; nr < 3; ++nr)
            bfr[nr] = *(const short8v*)(Wot + (size_t)(wc * 48 + nr * 16 + c16) * 192 + ks * 32 + kof);
        #pragma unroll
        for (int mr = 0; mr < 4; ++mr)
            #pragma unroll
            for (int nr = 0; nr < 3; ++nr)
                oacc[mr][nr] = __builtin_amdgcn_mfma_f32_16x16x32_bf16(
                    af[mr], bfr[nr], oacc[mr][nr], 0, 0, 0);
    }
    #pragma unroll
    for (int nr = 0; nr < 3; ++nr) {
        int col = wc * 48 + nr * 16 + c16;
        float b = bo[col];
        #pragma unroll
        for (int mr = 0; mr < 4; ++mr)
            #pragma unroll
            for (int reg = 0; reg < 4; ++reg) {
                oacc[mr][nr][reg] += b;
                int row = lbase + mr * 16 + hi2 * 4 + reg;
                Ybuf[row * 200 + col] = (short)f2bf(oacc[mr][nr][reg]);
            }
    }
    __syncthreads();

    // ---- stage1: z = [o,x] @ Wg + bg; gate; LN1 -> y
    f32x4 zacc[4][3];
    #pragma unroll
    for (int mr = 0; mr < 4; ++mr)
        #pragma unroll
        for (int nr = 0; nr < 3; ++nr) zacc[mr][nr] = (f32x4)(0.f);
    #pragma unroll 1
    for (int ks = 0; ks < 6; ++ks) {          // o half (from LDS)
        short8v af[4], bfr[3];
        #pragma unroll
        for (int mr = 0; mr < 4; ++mr)
            af[mr] = *(const short8v*)&Ybuf[(lbase + mr * 16 + c16) * 200 + ks * 32 + kof];
        #pragma unroll
        for (int nr = 0; nr < 3; ++nr)
            bfr[nr] = *(const short8v*)(Wgt + (size_t)(wc * 48 + nr * 16 + c16) * 384 + ks * 32 + kof);
        #pragma unroll
        for (int mr = 0; mr < 4; ++mr)
            #pragma unroll
            for (int nr = 0; nr < 3; ++nr)
                zacc[mr][nr] = __builtin_amdgcn_mfma_f32_16x16x32_bf16(
                    af[mr], bfr[nr], zacc[mr][nr], 0, 0, 0);
    }
    #pragma unroll 1
    for (int ks = 0; ks < 6; ++ks) {          // x half (from global)
        short8v af[4], bfr[3];
        #pragma unroll
        for (int mr = 0; mr < 4; ++mr)
            af[mr] = *(const short8v*)(xb + (size_t)rcm[mr] * 192 + ks * 32 + kof);
        #pragma unroll
        for (int nr = 0; nr < 3; ++nr)
            bfr[nr] = *(const short8v*)(Wgt + (size_t)(wc * 48 + nr * 16 + c16) * 384 + 192 + ks * 32 + kof);
        #pragma unroll
        for (int mr = 0; mr < 4; ++mr)
            #pragma unroll
            for (int nr = 0; nr < 3; ++nr)
                zacc[mr][nr] = __builtin_amdgcn_mfma_f32_16x16x32_bf16(
                    af[mr], bfr[nr], zacc[mr][nr], 0, 0, 0);
    }
    float s1p[4][4], s2p[4][4];
    #pragma unroll
    for (int mr = 0; mr < 4; ++mr)
        #pragma unroll
        for (int reg = 0; reg < 4; ++reg) {
            int gr = rbase + mr * 16 + hi2 * 4 + reg;
            int rcR = gr < M ? gr : M - 1;
            float s1 = 0.f, s2 = 0.f;
            #pragma unroll
            for (int nr = 0; nr < 3; ++nr) {
                int col = wc * 48 + nr * 16 + c16;
                float z = zacc[mr][nr][reg] + bg[col];
                float g = 1.f / (1.f + expf(-z));
                float xv = bf2f(xb[(size_t)rcR * 192 + col]);
                float val = g * oacc[mr][nr][reg] + (1.f - g) * xv;
                zacc[mr][nr][reg] = val;
                s1 += val; s2 += val * val;
            }
            #pragma unroll
            for (int mS = 1; mS < 16; mS <<= 1) {
                s1 += __shfl_xor(s1, mS, 64);
                s2 += __shfl_xor(s2, mS, 64);
            }
            s1p[mr][reg] = s1; s2p[mr][reg] = s2;
        }
    if (c16 == 0) {
        #pragma unroll
        for (int mr = 0; mr < 4; ++mr)
            #pragma unroll
            for (int reg = 0; reg < 4; ++reg) {
                int rowIdx = lbase + mr * 16 + hi2 * 4 + reg;
                red[0][wc][rowIdx] = s1p[mr][reg];
                red[1][wc][rowIdx] = s2p[mr][reg];
            }
    }
    __syncthreads();   // all stage1 Ybuf o-reads done; safe to overwrite with y
    #pragma unroll
    for (int mr = 0; mr < 4; ++mr)
        #pragma unroll
        for (int reg = 0; reg < 4; ++reg) {
            int rowIdx = lbase + mr * 16 + hi2 * 4 + reg;
            float S1 = red[0][0][rowIdx] + red[0][1][rowIdx] + red[0][2][rowIdx] + red[0][3][rowIdx];
            float S2 = red[1][0][rowIdx] + red[1][1][rowIdx] + red[1][2][rowIdx] + red[1][3][rowIdx];
            float mean = S1 * (1.f / 192.f);
            float var  = S2 * (1.f / 192.f) - mean * mean;
            float inv  = rsqrtf(var + 1e-5f);
            #pragma unroll
            for (int nr = 0; nr < 3; ++nr) {
                int col = wc * 48 + nr * 16 + c16;
                float yv = (zacc[mr][nr][reg] - mean) * inv * l1s[col] + l1b[col];
                Ybuf[rowIdx * 200 + col] = (short)f2bf(yv);
            }
        }
    __syncthreads();

    // ---- stage2: t = silu(y @ Wf1 + bf1), cols wc*96 + nr*16, nr<6
    f32x4 tacc[4][6];
    #pragma unroll
    for (int mr = 0; mr < 4; ++mr)
        #pragma unroll
        for (int nr = 0; nr < 6; ++nr) tacc[mr][nr] = (f32x4)(0.f);
    #pragma unroll 1
    for (int ks = 0; ks < 6; ++ks) {
        short8v af[4], bfr[6];
        #pragma unroll
        for (int mr = 0; mr < 4; ++mr)
            af[mr] = *(const short8v*)&Ybuf[(lbase + mr * 16 + c16) * 200 + ks * 32 + kof];
        #pragma unroll
        for (int nr = 0; nr < 6; ++nr)
            bfr[nr] = *(const short8v*)(Wf1t + (size_t)(wc * 96 + nr * 16 + c16) * 192 + ks * 32 + kof);
        #pragma unroll
        for (int mr = 0; mr < 4; ++mr)
            #pragma unroll
            for (int nr = 0; nr < 6; ++nr)
                tacc[mr][nr] = __builtin_amdgcn_mfma_f32_16x16x32_bf16(
                    af[mr], bfr[nr], tacc[mr][nr], 0, 0, 0);
    }
    #pragma unroll
    for (int nr = 0; nr < 6; ++nr) {
        int col = wc * 96 + nr * 16 + c16;
        float b = bf1[col];
        #pragma unroll
        for (int mr = 0; mr < 4; ++mr)
            #pragma unroll
            for (int reg = 0; reg < 4; ++reg) {
                float z = tacc[mr][nr][reg] + b;
                float t = z / (1.f + expf(-z));
                int row = lbase + mr * 16 + hi2 * 4 + reg;
                Fbuf[row * 392 + col] = (short)f2bf(t);
            }
    }
    __syncthreads();

    // ---- stage3: out = LN2(y + t @ Wf2 + bf2)
    f32x4 facc[4][3];
    #pragma unroll
    for (int mr = 0; mr < 4; ++mr)
        #pragma unroll
        for (int nr = 0; nr < 3; ++nr) facc[mr][nr] = (f32x4)(0.f);
    #pragma unroll 1
    for (int ks = 0; ks < 12; ++ks) {
        short8v af[4], bfr[3];
        #pragma unroll
        for (int mr = 0; mr < 4; ++mr)
            af[mr] = *(const short8v*)&Fbuf[(lbase + mr * 16 + c16) * 392 + ks * 32 + kof];
        #pragma unroll
        for (int nr = 0; nr < 3; ++nr)
            bfr[nr] = *(const short8v*)(Wf2t + (size_t)(wc * 48 + nr * 16 + c16) * 384 + ks * 32 + kof);
        #pragma unroll
        for (int mr = 0; mr < 4; ++mr)
            #pragma unroll
            for (int nr = 0; nr < 3; ++nr)
                facc[mr][nr] = __builtin_amdgcn_mfma_f32_16x16x32_bf16(
                    af[mr], bfr[nr], facc[mr][nr], 0, 0, 0);
    }
    float s1q[4][4], s2q[4][4];
    #pragma unroll
    for (int mr = 0; mr < 4; ++mr)
        #pragma unroll
        for (int reg = 0; reg < 4; ++reg) {
            int rowIdx = lbase + mr * 16 + hi2 * 4 + reg;
            float s1 = 0.f, s2 = 0.f;
            #pragma unroll
            for (int nr = 0; nr < 3; ++nr) {
                int col = wc * 48 + nr * 16 + c16;
                float val = facc[mr][nr][reg] + bf2[col] + bf2f((u16)Ybuf[rowIdx * 200 + col]);
                facc[mr][nr][reg] = val;
                s1 += val; s2 += val * val;
            }
            #pragma unroll
            for (int mS = 1; mS < 16; mS <<= 1) {
                s1 += __shfl_xor(s1, mS, 64);
                s2 += __shfl_xor(s2, mS, 64);
            }
            s1q[mr][reg] = s1; s2q[mr][reg] = s2;
        }
    if (c16 == 0) {
        #pragma unroll
        for (int mr = 0; mr < 4; ++mr)
            #pragma unroll
            for (int reg = 0; reg < 4; ++reg) {
                int rowIdx = lbase + mr * 16 + hi2 * 4 + reg;
                red[0][wc][rowIdx] = s1q[mr][reg];
                red[1][wc][rowIdx] = s2q[mr][reg];
            }
    }
    __syncthreads();
    #pragma unroll
    for (int mr = 0; mr < 4; ++mr)
        #pragma unroll
        for (int reg = 0; reg < 4; ++reg) {
            int rowIdx = lbase + mr * 16 + hi2 * 4 + reg;
            int r = m0 + rowIdx;
            if (r >= M) continue;
            float S1 = red[0][0][rowIdx] + red[0][1][rowIdx] + red[0][2][rowIdx] + red[0][3][rowIdx];
            float S2 = red[1][0][rowIdx] + red[1][1][rowIdx] + red[1][2][rowIdx] + red[1][3][rowIdx];
            float mean = S1 * (1.f / 192.f);
            float var  = S2 * (1.f / 192.f) - mean * mean;
            float inv  = rsqrtf(var + 1e-5f);
            #pragma unroll
            for (int nr = 0; nr < 3; ++nr) {
                int col = wc * 48 + nr * 16 + c16;
                out[(size_t)r * 192 + col] =
                    (facc[mr][nr][reg] - mean) * inv * l2s[col] + l2b[col];
            }
        }
}

// ---------------------------------------------------------------- launcher
extern "C" void kernel_launch(void* const* d_in, const int* in_sizes, int n_in,
                              void* d_out, int out_size, void* d_ws, size_t ws_size,
                              hipStream_t stream) {
    const float* x   = (const float*)d_in[0];
    const float* ef  = (const float*)d_in[1];
    const int*   ei  = (const int*)d_in[2];
    const float* Wq  = (const float*)d_in[3];
    const float* Wk  = (const float*)d_in[4];
    const float* Wv  = (const float*)d_in[5];
    const float* We  = (const float*)d_in[6];
    const float* Wo  = (const float*)d_in[7];
    const float* bo  = (const float*)d_in[8];
    const float* Wg  = (const float*)d_in[9];
    const float* bg  = (const float*)d_in[10];
    const float* l1s = (const float*)d_in[11];
    const float* l1b = (const float*)d_in[12];
    const float* Wf1 = (const float*)d_in[13];
    const float* bf1 = (const float*)d_in[14];
    const float* Wf2 = (const float*)d_in[15];
    const float* bf2 = (const float*)d_in[16];
    const float* l2s = (const float*)d_in[17];
    const float* l2b = (const float*)d_in[18];

    int N = in_sizes[0] / Dm;
    int E = in_sizes[1] / DEe;
    float* out = (float*)d_out;

    char* wp = (char*)d_ws;
    auto alloc = [&](size_t bytes) -> void* {
        void* p = wp;
        wp += (bytes + 255) & ~(size_t)255;
        return p;
    };
    size_t NF = (size_t)N * Dm;
    u16*   xb     = (u16*)alloc(NF * 2);
    u16*   qkvb   = (u16*)alloc((size_t)N * 576 * 2);
    u16*   aggb   = (u16*)alloc(NF * 2);
    float* scb    = (float*)alloc((size_t)E * 8 * 4);
    int*   sbuf   = (int*)  alloc((size_t)E * 4);
    int*   degcur = (int*)  alloc((size_t)2 * N * 4);
    int*   offs   = (int*)  alloc((size_t)(N + 1) * 4);
    u16*   Wqkvt  = (u16*)alloc((size_t)576 * 192 * 2);
    u16*   Wot    = (u16*)alloc((size_t)192 * 192 * 2);
    u16*   Wgt    = (u16*)alloc((size_t)192 * 384 * 2);
    u16*   Wf1t   = (u16*)alloc((size_t)384 * 192 * 2);
    u16*   Wf2t   = (u16*)alloc((size_t)192 * 384 * 2);
    int* deg = degcur;
    int* cur = degcur + N;

    int gm128 = (N + 127) / 128;

    prep_w<<<dim3(1440), 256, 0, stream>>>(Wq, Wk, Wv, Wo, Wg, Wf1, Wf2,
        Wqkvt, Wot, Wgt, Wf1t, Wf2t);
    xconv<<<dim3((N * Dm / 4 + 255) / 256), 256, 0, stream>>>(x, N * Dm / 4, xb);
    zero_ints<<<dim3((2 * N + 255) / 256), 256, 0, stream>>>(degcur, 2 * N);
    count_deg<<<dim3((E + 255) / 256), 256, 0, stream>>>(ei, E, deg);
    scan_kernel<<<dim3(1), 1024, 0, stream>>>(deg, N, offs);

    qkv_gemm<<<dim3(gm128, 3), 512, 0, stream>>>(xb, N, Wqkvt, qkvb);

    edge_prep<<<dim3((E + 31) / 32), 256, 0, stream>>>(ei, E, ef, We,
        offs, cur, scb, sbuf);
    agg_fused<<<dim3((N + 3) / 4), 256, 0, stream>>>(qkvb, scb, sbuf, offs, N, aggb);

    chain_fused<<<dim3(gm128), 512, 0, stream>>>(aggb, xb, N,
        Wot, bo, Wgt, bg, l1s, l1b, Wf1t, bf1, Wf2t, bf2, l2s, l2b, out);
}